// Round 4
// baseline (305.328 us; speedup 1.0000x reference)
//
#include <hip/hip_runtime.h>
#include <cstdint>
#include <cstddef>

using short8 = __attribute__((ext_vector_type(8))) short;
using f32x4  = __attribute__((ext_vector_type(4))) float;
using u16x4  = __attribute__((ext_vector_type(4))) unsigned short;

#define DEV __device__ __forceinline__

DEV unsigned short f2bf(float f) {
  unsigned int u = __builtin_bit_cast(unsigned int, f);
  u += 0x7fffu + ((u >> 16) & 1u);          // RNE
  return (unsigned short)(u >> 16);
}
DEV float bf2f(unsigned short h) {
  unsigned int u = ((unsigned int)h) << 16;
  return __builtin_bit_cast(float, u);
}

// direct global->LDS, width 16B (m97 lever). LDS dest = wave-uniform base + lane*16.
#define GLL16(gp, lp)                                                          \
  __builtin_amdgcn_global_load_lds(                                            \
      (const __attribute__((address_space(1))) char*)(const char*)(gp),        \
      (__attribute__((address_space(3))) char*)(char*)(lp), 16, 0, 0)

constexpr int BATCH = 2, SEQ = 2048, DMODEL = 2048, NH = 16, NKVH = 4, DH = 128;
constexpr int MROWS = BATCH * SEQ;            // 4096
constexpr int NQKV  = DMODEL + 2 * NKVH * DH; // 3072 (Q | K | V)
constexpr int KOFF  = DMODEL;                 // 2048
constexpr int VOFF  = DMODEL + NKVH * DH;     // 2560
constexpr float SM_L2 = 0.12751388158f;       // (1/sqrt(128)) * log2(e), folded into Q at RoPE

// ---------------- prep kernels ----------------

__global__ void k_tables(float* __restrict__ tc, float* __restrict__ ts) {
  int id = blockIdx.x * 256 + threadIdx.x;    // SEQ*64 total
  int pos = id >> 6, i = id & 63;
  float freq = __expf(-(float)i * 0.14391157f);
  float ang = (float)pos * freq;
  tc[id] = cosf(ang);
  ts[id] = sinf(ang);
}

__global__ void k_castx(const float* __restrict__ x, unsigned short* __restrict__ xb) {
  int id = blockIdx.x * 256 + threadIdx.x;    // MROWS*DMODEL/4 total
  float4 v = ((const float4*)x)[id];
  u16x4 o = { f2bf(v.x), f2bf(v.y), f2bf(v.z), f2bf(v.w) };
  ((u16x4*)xb)[id] = o;
}

// src: K(2048) x N fp32 row-major  ->  dst: N x 2048 bf16 row-major
__global__ __launch_bounds__(256) void k_wtrans(const float* __restrict__ src,
                                                unsigned short* __restrict__ dst, int N) {
  __shared__ float tile[32][33];
  int n0 = blockIdx.x * 32, k0 = blockIdx.y * 32;
  int tx = threadIdx.x, ty = threadIdx.y;     // 32 x 8
  #pragma unroll
  for (int r = ty; r < 32; r += 8)
    tile[r][tx] = src[(size_t)(k0 + r) * N + n0 + tx];
  __syncthreads();
  #pragma unroll
  for (int r = ty; r < 32; r += 8)
    dst[(size_t)(n0 + r) * 2048 + k0 + tx] = f2bf(tile[tx][r]);
}

// V region of qkv -> vt[b][kvh][d=128][s=2048]  (bf16 -> bf16 transpose)
__global__ __launch_bounds__(256) void k_vtrans(const unsigned short* __restrict__ qkv,
                                                unsigned short* __restrict__ vt) {
  __shared__ unsigned short tile[32][33];
  int s0 = blockIdx.x * 32, d0 = blockIdx.y * 32;
  int bk = blockIdx.z;                         // b*4 + kvh
  const unsigned short* src = qkv + (size_t)(bk >> 2) * SEQ * NQKV + VOFF + (bk & 3) * DH;
  unsigned short* dst = vt + ((size_t)bk * DH + d0) * SEQ + s0;
  int tx = threadIdx.x, ty = threadIdx.y;      // 32 x 8
  #pragma unroll
  for (int r = ty; r < 32; r += 8)
    tile[r][tx] = src[(size_t)(s0 + r) * NQKV + d0 + tx];
  __syncthreads();
  #pragma unroll
  for (int r = ty; r < 32; r += 8)
    dst[(size_t)r * SEQ + tx] = tile[tx][r];
}

// ---------------- GEMM: C[m][n] = sum_k A[m][k]*Bt[n][k]  (m97 + XCD swizzle) ----

constexpr int BM = 128, BN = 128, BK = 32;

template <bool OUTF32>
__global__ __launch_bounds__(256) void k_gemm_bt(
    const unsigned short* __restrict__ A,   // M x K bf16
    const unsigned short* __restrict__ Bt,  // N x K bf16
    void* __restrict__ C, int M, int N, int K) {
  __shared__ unsigned short As[BM * BK];
  __shared__ unsigned short Bs[BN * BK];
  const int t = threadIdx.x;
  const int l = t & 63, w = t >> 6;
  const int wm = w >> 1, wn = w & 1;
  // XCD-aware swizzle (T1): nwg % 8 == 0 for both GEMMs here
  const int gx = gridDim.x;
  const int nwg = gx * gridDim.y;
  const int idl = blockIdx.y * gx + blockIdx.x;
  const int swz = (idl & 7) * (nwg >> 3) + (idl >> 3);
  const int m0 = (swz / gx) * BM, n0 = (swz % gx) * BN;
  const int rl = l & 15, kg = l >> 4;

  f32x4 acc[4][4] = {};

  const int sr = t >> 2;
  const int gq = (t & 3) ^ (sr & 3);
  const unsigned short* aP0 = A  + (size_t)(m0 + sr) * K + gq * 8;
  const unsigned short* aP1 = A  + (size_t)(m0 + 64 + sr) * K + gq * 8;
  const unsigned short* bP0 = Bt + (size_t)(n0 + sr) * K + gq * 8;
  const unsigned short* bP1 = Bt + (size_t)(n0 + 64 + sr) * K + gq * 8;
  char* ldsA = (char*)As;
  char* ldsB = (char*)Bs;
  const int wb = w * 1024;

  const int nk = K / BK;
  for (int kt = 0; kt < nk; ++kt) {
    const int ko = kt * BK;
    __syncthreads();
    GLL16(aP0 + ko, ldsA + wb);
    GLL16(aP1 + ko, ldsA + 4096 + wb);
    GLL16(bP0 + ko, ldsB + wb);
    GLL16(bP1 + ko, ldsB + 4096 + wb);
    __syncthreads();
    short8 aF[4], bF[4];
    #pragma unroll
    for (int mi = 0; mi < 4; ++mi) {
      int r = wm * 64 + mi * 16 + rl;
      aF[mi] = *(const short8*)(ldsA + r * 64 + ((kg ^ (r & 3)) * 16));
    }
    #pragma unroll
    for (int ni = 0; ni < 4; ++ni) {
      int r = wn * 64 + ni * 16 + rl;
      bF[ni] = *(const short8*)(ldsB + r * 64 + ((kg ^ (r & 3)) * 16));
    }
    #pragma unroll
    for (int mi = 0; mi < 4; ++mi)
      #pragma unroll
      for (int ni = 0; ni < 4; ++ni)
        acc[mi][ni] = __builtin_amdgcn_mfma_f32_16x16x32_bf16(aF[mi], bF[ni], acc[mi][ni], 0, 0, 0);
  }

  // C/D layout (m89-verified): col = lane&15, row = (lane>>4)*4 + reg
  #pragma unroll
  for (int mi = 0; mi < 4; ++mi) {
    #pragma unroll
    for (int ni = 0; ni < 4; ++ni) {
      int row = m0 + wm * 64 + mi * 16 + kg * 4;
      int col = n0 + wn * 64 + ni * 16 + rl;
      #pragma unroll
      for (int r = 0; r < 4; ++r) {
        if constexpr (OUTF32)
          ((float*)C)[(size_t)(row + r) * N + col] = acc[mi][ni][r];
        else
          ((unsigned short*)C)[(size_t)(row + r) * N + col] = f2bf(acc[mi][ni][r]);
      }
    }
  }
}

// ---------------- RoPE (interleaved pairs) on Q and K; Q pre-scaled by SM_L2 --

__global__ void k_rope(unsigned short* __restrict__ qkv,
                       const float* __restrict__ tc, const float* __restrict__ ts) {
  int id = blockIdx.x * 256 + threadIdx.x;     // MROWS * 1280
  int row = id / 1280, p = id % 1280;
  int col, d;
  bool isq = (p < 1024);
  if (isq) { col = 2 * p;               d = p & 63; }
  else     { int pk = p - 1024; col = KOFF + 2 * pk; d = pk & 63; }
  int s = row & (SEQ - 1);
  float c = tc[s * 64 + d], sn = ts[s * 64 + d];
  unsigned int* pp = (unsigned int*)(qkv + (size_t)row * NQKV + col);
  unsigned int v = *pp;
  float x0 = bf2f((unsigned short)(v & 0xffffu));
  float x1 = bf2f((unsigned short)(v >> 16));
  float y0 = x0 * c - x1 * sn;
  float y1 = x1 * c + x0 * sn;
  if (isq) { y0 *= SM_L2; y1 *= SM_L2; }       // fold softmax scale * log2e into Q
  *pp = (unsigned int)f2bf(y0) | ((unsigned int)f2bf(y1) << 16);
}

// ---------------- flash attention, causal, GQA ------------------------------
// 8 waves x 16 q-rows (QB=128), KVBLK=64; reg-staged K/V with async split (T14):
// issue global loads for tile t+1 before computing t, ds_write (swizzled) after.

constexpr int QB = 128, KB = 64;
constexpr float THR = 8.0f;                    // defer-max threshold (log2 domain)

__global__ __launch_bounds__(512) void k_attn(const unsigned short* __restrict__ qkv,
                                              const unsigned short* __restrict__ vt,
                                              unsigned short* __restrict__ obuf) {
  __shared__ unsigned short Ks[KB * DH];        // [64][128], chunk-XOR ^(row&7)
  __shared__ unsigned short Vs[DH * KB];        // [128][64], chunk-XOR ^(row&7)
  __shared__ unsigned short Pw[8][16 * 72];     // per-wave P, padded stride 72

  const int t = threadIdx.x, l = t & 63, w = t >> 6;
  const int rl = l & 15, kg = l >> 4;

  // complementary-pair decode: ids i and i+256 get q-tiles qt and 15-qt
  const int id = blockIdx.x;                    // [0, 512)
  const int b = id >> 8;
  const int u = id & 255;
  const int h = u >> 4;
  const int qtr = u & 15;
  const int qt = b ? (15 - qtr) : qtr;
  const int q0 = qt * QB;
  const int kvh = h >> 2;

  const unsigned short* qbase = qkv + (size_t)b * SEQ * NQKV;
  const unsigned short* kbase = qbase + KOFF + kvh * DH;
  const unsigned short* vtb = vt + (size_t)(b * NKVH + kvh) * DH * SEQ;

  // reg-staging geometry: K chunks c = t, t+512 (row=c>>4, q=c&15);
  //                       V chunks c = t, t+512 (row=c>>3, q=c&7)
  int krow0 = t >> 4, kq0 = t & 15;
  int krow1 = (t + 512) >> 4, kq1 = (t + 512) & 15;
  int vrow0 = t >> 3, vq0 = t & 7;
  int vrow1 = (t + 512) >> 3, vq1 = (t + 512) & 7;
  const unsigned short* gK0 = kbase + (size_t)krow0 * NQKV + kq0 * 8;
  const unsigned short* gK1 = kbase + (size_t)krow1 * NQKV + kq1 * 8;
  const unsigned short* gV0 = vtb + (size_t)vrow0 * SEQ + vq0 * 8;
  const unsigned short* gV1 = vtb + (size_t)vrow1 * SEQ + vq1 * 8;
  char* lK0 = (char*)Ks + krow0 * 256 + ((kq0 ^ (krow0 & 7)) << 4);
  char* lK1 = (char*)Ks + krow1 * 256 + ((kq1 ^ (krow1 & 7)) << 4);
  char* lV0 = (char*)Vs + vrow0 * 128 + ((vq0 ^ (vrow0 & 7)) << 4);
  char* lV1 = (char*)Vs + vrow1 * 128 + ((vq1 ^ (vrow1 & 7)) << 4);

  const int qw0 = q0 + w * 16;

  // Q fragments hoisted: A[row=rl][k=kg*8+j], 4 k-steps (Q pre-scaled by SM_L2)
  short8 qF[4];
  {
    const size_t qr = (size_t)(qw0 + rl) * NQKV + h * DH;
    #pragma unroll
    for (int ks = 0; ks < 4; ++ks)
      qF[ks] = *(const short8*)(qbase + qr + ks * 32 + kg * 8);
  }

  f32x4 Oc[8] = {};
  float mr[4], lr[4];
  #pragma unroll
  for (int r = 0; r < 4; ++r) { mr[r] = -3e38f; lr[r] = 0.f; }

  unsigned short* pw = Pw[w];
  const int nt = q0 / KB + 2;                   // kv tiles up to (incl.) diagonal

  // prologue: stage tile 0
  float4 kr0, kr1, vr0, vr1;
  kr0 = *(const float4*)gK0;  kr1 = *(const float4*)gK1;
  vr0 = *(const float4*)gV0;  vr1 = *(const float4*)gV1;
  *(float4*)lK0 = kr0;  *(float4*)lK1 = kr1;
  *(float4*)lV0 = vr0;  *(float4*)lV1 = vr1;
  __syncthreads();

  for (int tt = 0; tt < nt; ++tt) {
    const int kv0 = tt * KB;
    const bool more = (tt + 1 < nt);
    if (more) {                                  // issue next-tile loads early (T14)
      const size_t koff = (size_t)(kv0 + KB) * NQKV;
      kr0 = *(const float4*)(gK0 + koff);
      kr1 = *(const float4*)(gK1 + koff);
      vr0 = *(const float4*)(gV0 + kv0 + KB);
      vr1 = *(const float4*)(gV1 + kv0 + KB);
    }

    if (kv0 < qw0 + 16) {                        // not fully masked (wave-uniform)
      // S = Q K^T (log2-domain): St[n], kv col tiles n of 16
      f32x4 St[4] = {};
      #pragma unroll
      for (int n = 0; n < 4; ++n) {
        const int krow = n * 16 + rl;
        #pragma unroll
        for (int ks = 0; ks < 4; ++ks) {
          short8 kF = *(const short8*)&Ks[krow * DH + (((ks * 4 + kg) ^ (rl & 7)) << 3)];
          St[n] = __builtin_amdgcn_mfma_f32_16x16x32_bf16(qF[ks], kF, St[n], 0, 0, 0);
        }
      }

      const bool diag = (kv0 + KB - 1) > qw0;    // diagonal tile -> needs masking
      // pass 1: mask + row max
      float mxv[4];
      bool need = false;
      #pragma unroll
      for (int r = 0; r < 4; ++r) {
        const int qg = qw0 + kg * 4 + r;
        float mx = -3e38f;
        #pragma unroll
        for (int n = 0; n < 4; ++n) {
          float s = St[n][r];
          if (diag && (kv0 + n * 16 + rl > qg)) s = -3e38f;
          St[n][r] = s;
          mx = fmaxf(mx, s);
        }
        #pragma unroll
        for (int dd = 1; dd < 16; dd <<= 1) mx = fmaxf(mx, __shfl_xor(mx, dd, 16));
        mxv[r] = mx;
        need = need || (mx > mr[r] + THR);
      }
      // deferred rescale (T13): only when some row's max grew past THR
      if (__any(need)) {
        float sfv[4];
        #pragma unroll
        for (int r = 0; r < 4; ++r) {
          const float mnew = fmaxf(mr[r], mxv[r]);
          sfv[r] = exp2f(mr[r] - mnew);
          mr[r] = mnew;
          lr[r] *= sfv[r];
        }
        #pragma unroll
        for (int c = 0; c < 8; ++c)
          #pragma unroll
          for (int r = 0; r < 4; ++r) Oc[c][r] *= sfv[r];
      }
      // pass 2: exp2, row-sum, P -> LDS
      #pragma unroll
      for (int r = 0; r < 4; ++r) {
        const int pr = kg * 4 + r;
        float rs = 0.f;
        #pragma unroll
        for (int n = 0; n < 4; ++n) {
          float e = exp2f(St[n][r] - mr[r]);
          rs += e;
          pw[pr * 72 + n * 16 + rl] = f2bf(e);
        }
        #pragma unroll
        for (int dd = 1; dd < 16; dd <<= 1) rs += __shfl_xor(rs, dd, 16);
        lr[r] += rs;
      }

      // PV: A = P[16][64] (row=rl, k=kv), B = V (col=d=rl, k=kv) from Vs rows
      short8 pF[2];
      #pragma unroll
      for (int ks2 = 0; ks2 < 2; ++ks2)
        pF[ks2] = *(const short8*)&pw[rl * 72 + ks2 * 32 + kg * 8];
      #pragma unroll
      for (int c = 0; c < 8; ++c) {
        const int vrow = c * 16 + rl;
        #pragma unroll
        for (int ks2 = 0; ks2 < 2; ++ks2) {
          short8 vF = *(const short8*)&Vs[vrow * KB + (((ks2 * 4 + kg) ^ (rl & 7)) << 3)];
          Oc[c] = __builtin_amdgcn_mfma_f32_16x16x32_bf16(pF[ks2], vF, Oc[c], 0, 0, 0);
        }
      }
    }

    __syncthreads();                             // all waves done reading LDS[t]
    if (more) {                                  // write prefetched tile t+1
      *(float4*)lK0 = kr0;  *(float4*)lK1 = kr1;
      *(float4*)lV0 = vr0;  *(float4*)lV1 = vr1;
    }
    __syncthreads();                             // LDS[t+1] visible
  }

  // epilogue: O /= l, write bf16 [b*S+s][h*128+d]
  float inv[4];
  #pragma unroll
  for (int r = 0; r < 4; ++r) inv[r] = 1.0f / lr[r];
  #pragma unroll
  for (int c = 0; c < 8; ++c)
    #pragma unroll
    for (int r = 0; r < 4; ++r) {
      int row = b * SEQ + qw0 + kg * 4 + r;
      obuf[(size_t)row * DMODEL + h * DH + c * 16 + rl] = f2bf(Oc[c][r] * inv[r]);
    }
}

// ---------------- launch ----------------------------------------------------

extern "C" void kernel_launch(void* const* d_in, const int* in_sizes, int n_in,
                              void* d_out, int out_size, void* d_ws, size_t ws_size,
                              hipStream_t stream) {
  const float* x  = (const float*)d_in[0];
  const float* wq = (const float*)d_in[1];
  const float* wk = (const float*)d_in[2];
  const float* wv = (const float*)d_in[3];
  const float* wo = (const float*)d_in[4];
  float* out = (float*)d_out;

  unsigned short* xb  = (unsigned short*)d_ws;                 // 4096x2048
  unsigned short* wT  = xb  + (size_t)MROWS * DMODEL;          // 3072x2048 (q|k|v transposed)
  unsigned short* woT = wT  + (size_t)NQKV * DMODEL;           // 2048x2048
  unsigned short* qkv = woT + (size_t)DMODEL * DMODEL;         // 4096x3072
  unsigned short* ob  = qkv + (size_t)MROWS * NQKV;            // 4096x2048
  float* tc = (float*)(ob + (size_t)MROWS * DMODEL);           // 2048x64
  float* ts = tc + SEQ * 64;
  // vt reuses the wT region (wT dead after the QKV GEMM)
  unsigned short* vtG = wT;

  k_tables<<<dim3(SEQ * 64 / 256), dim3(256), 0, stream>>>(tc, ts);
  k_castx<<<dim3(MROWS * DMODEL / 4 / 256), dim3(256), 0, stream>>>(x, xb);
  k_wtrans<<<dim3(DMODEL / 32, 64), dim3(32, 8), 0, stream>>>(wq, wT, DMODEL);
  k_wtrans<<<dim3(NKVH * DH / 32, 64), dim3(32, 8), 0, stream>>>(wk, wT + (size_t)DMODEL * 2048, NKVH * DH);
  k_wtrans<<<dim3(NKVH * DH / 32, 64), dim3(32, 8), 0, stream>>>(wv, wT + (size_t)VOFF * 2048, NKVH * DH);
  k_wtrans<<<dim3(DMODEL / 32, 64), dim3(32, 8), 0, stream>>>(wo, woT, DMODEL);

  k_gemm_bt<false><<<dim3(NQKV / BN, MROWS / BM), dim3(256), 0, stream>>>(
      xb, wT, qkv, MROWS, NQKV, DMODEL);
  k_rope<<<dim3(MROWS * 1280 / 256), dim3(256), 0, stream>>>(qkv, tc, ts);
  k_vtrans<<<dim3(SEQ / 32, DH / 32, BATCH * NKVH), dim3(32, 8), 0, stream>>>(qkv, vtG);
  k_attn<<<dim3(512), dim3(512), 0, stream>>>(qkv, vtG, ob);
  k_gemm_bt<true><<<dim3(DMODEL / BN, MROWS / BM), dim3(256), 0, stream>>>(
      ob, woT, out, MROWS, DMODEL, DMODEL);
}

// Round 5
// 245.819 us; speedup vs baseline: 1.2421x; 1.2421x over previous
//
#include <hip/hip_runtime.h>
#include <cstdint>
#include <cstddef>

using short8 = __attribute__((ext_vector_type(8))) short;
using f32x4  = __attribute__((ext_vector_type(4))) float;
using u16x4  = __attribute__((ext_vector_type(4))) unsigned short;

#define DEV __device__ __forceinline__

DEV unsigned short f2bf(float f) {
  unsigned int u = __builtin_bit_cast(unsigned int, f);
  u += 0x7fffu + ((u >> 16) & 1u);          // RNE
  return (unsigned short)(u >> 16);
}
DEV float bf2f(unsigned short h) {
  unsigned int u = ((unsigned int)h) << 16;
  return __builtin_bit_cast(float, u);
}
DEV unsigned int cvtpk_bf16(float lo, float hi) {  // d.lo16=bf16(lo), d.hi16=bf16(hi)
  unsigned int d;
  asm("v_cvt_pk_bf16_f32 %0, %1, %2" : "=v"(d) : "v"(lo), "v"(hi));
  return d;
}

// direct global->LDS, width 16B (m97 lever). LDS dest = wave-uniform base + lane*16.
#define GLL16(gp, lp)                                                          \
  __builtin_amdgcn_global_load_lds(                                            \
      (const __attribute__((address_space(1))) char*)(const char*)(gp),        \
      (__attribute__((address_space(3))) char*)(char*)(lp), 16, 0, 0)

constexpr int BATCH = 2, SEQ = 2048, DMODEL = 2048, NH = 16, NKVH = 4, DH = 128;
constexpr int MROWS = BATCH * SEQ;            // 4096
constexpr int NQKV  = DMODEL + 2 * NKVH * DH; // 3072 (Q | K | V)
constexpr int KOFF  = DMODEL;                 // 2048
constexpr int VOFF  = DMODEL + NKVH * DH;     // 2560
constexpr float SM_L2 = 0.12751388158f;       // (1/sqrt(128)) * log2(e), folded into Q at RoPE

// ---------------- prep kernels ----------------

__global__ void k_tables(float* __restrict__ tc, float* __restrict__ ts) {
  int id = blockIdx.x * 256 + threadIdx.x;    // SEQ*64 total
  int pos = id >> 6, i = id & 63;
  float freq = __expf(-(float)i * 0.14391157f);
  float ang = (float)pos * freq;
  tc[id] = cosf(ang);
  ts[id] = sinf(ang);
}

__global__ void k_castx(const float* __restrict__ x, unsigned short* __restrict__ xb) {
  int id = blockIdx.x * 256 + threadIdx.x;    // MROWS*DMODEL/4 total
  float4 v = ((const float4*)x)[id];
  u16x4 o = { f2bf(v.x), f2bf(v.y), f2bf(v.z), f2bf(v.w) };
  ((u16x4*)xb)[id] = o;
}

// src: K(2048) x N fp32 row-major  ->  dst: N x 2048 bf16 row-major
__global__ __launch_bounds__(256) void k_wtrans(const float* __restrict__ src,
                                                unsigned short* __restrict__ dst, int N) {
  __shared__ float tile[32][33];
  int n0 = blockIdx.x * 32, k0 = blockIdx.y * 32;
  int tx = threadIdx.x, ty = threadIdx.y;     // 32 x 8
  #pragma unroll
  for (int r = ty; r < 32; r += 8)
    tile[r][tx] = src[(size_t)(k0 + r) * N + n0 + tx];
  __syncthreads();
  #pragma unroll
  for (int r = ty; r < 32; r += 8)
    dst[(size_t)(n0 + r) * 2048 + k0 + tx] = f2bf(tile[tx][r]);
}

// V region of qkv -> vt[b][kvh][d=128][s=2048]  (bf16 -> bf16 transpose)
__global__ __launch_bounds__(256) void k_vtrans(const unsigned short* __restrict__ qkv,
                                                unsigned short* __restrict__ vt) {
  __shared__ unsigned short tile[32][33];
  int s0 = blockIdx.x * 32, d0 = blockIdx.y * 32;
  int bk = blockIdx.z;                         // b*4 + kvh
  const unsigned short* src = qkv + (size_t)(bk >> 2) * SEQ * NQKV + VOFF + (bk & 3) * DH;
  unsigned short* dst = vt + ((size_t)bk * DH + d0) * SEQ + s0;
  int tx = threadIdx.x, ty = threadIdx.y;      // 32 x 8
  #pragma unroll
  for (int r = ty; r < 32; r += 8)
    tile[r][tx] = src[(size_t)(s0 + r) * NQKV + d0 + tx];
  __syncthreads();
  #pragma unroll
  for (int r = ty; r < 32; r += 8)
    dst[(size_t)r * SEQ + tx] = tile[tx][r];
}

// ---------------- GEMM: C[m][n] = sum_k A[m][k]*Bt[n][k]  (m97 + XCD swizzle) ----

constexpr int BM = 128, BN = 128, BK = 32;

template <bool OUTF32>
__global__ __launch_bounds__(256) void k_gemm_bt(
    const unsigned short* __restrict__ A,   // M x K bf16
    const unsigned short* __restrict__ Bt,  // N x K bf16
    void* __restrict__ C, int M, int N, int K) {
  __shared__ unsigned short As[BM * BK];
  __shared__ unsigned short Bs[BN * BK];
  const int t = threadIdx.x;
  const int l = t & 63, w = t >> 6;
  const int wm = w >> 1, wn = w & 1;
  // XCD-aware swizzle (T1): nwg % 8 == 0 for both GEMMs here
  const int gx = gridDim.x;
  const int nwg = gx * gridDim.y;
  const int idl = blockIdx.y * gx + blockIdx.x;
  const int swz = (idl & 7) * (nwg >> 3) + (idl >> 3);
  const int m0 = (swz / gx) * BM, n0 = (swz % gx) * BN;
  const int rl = l & 15, kg = l >> 4;

  f32x4 acc[4][4] = {};

  const int sr = t >> 2;
  const int gq = (t & 3) ^ (sr & 3);
  const unsigned short* aP0 = A  + (size_t)(m0 + sr) * K + gq * 8;
  const unsigned short* aP1 = A  + (size_t)(m0 + 64 + sr) * K + gq * 8;
  const unsigned short* bP0 = Bt + (size_t)(n0 + sr) * K + gq * 8;
  const unsigned short* bP1 = Bt + (size_t)(n0 + 64 + sr) * K + gq * 8;
  char* ldsA = (char*)As;
  char* ldsB = (char*)Bs;
  const int wb = w * 1024;

  const int nk = K / BK;
  for (int kt = 0; kt < nk; ++kt) {
    const int ko = kt * BK;
    __syncthreads();
    GLL16(aP0 + ko, ldsA + wb);
    GLL16(aP1 + ko, ldsA + 4096 + wb);
    GLL16(bP0 + ko, ldsB + wb);
    GLL16(bP1 + ko, ldsB + 4096 + wb);
    __syncthreads();
    short8 aF[4], bF[4];
    #pragma unroll
    for (int mi = 0; mi < 4; ++mi) {
      int r = wm * 64 + mi * 16 + rl;
      aF[mi] = *(const short8*)(ldsA + r * 64 + ((kg ^ (r & 3)) * 16));
    }
    #pragma unroll
    for (int ni = 0; ni < 4; ++ni) {
      int r = wn * 64 + ni * 16 + rl;
      bF[ni] = *(const short8*)(ldsB + r * 64 + ((kg ^ (r & 3)) * 16));
    }
    #pragma unroll
    for (int mi = 0; mi < 4; ++mi)
      #pragma unroll
      for (int ni = 0; ni < 4; ++ni)
        acc[mi][ni] = __builtin_amdgcn_mfma_f32_16x16x32_bf16(aF[mi], bF[ni], acc[mi][ni], 0, 0, 0);
  }

  // C/D layout (m89-verified): col = lane&15, row = (lane>>4)*4 + reg
  #pragma unroll
  for (int mi = 0; mi < 4; ++mi) {
    #pragma unroll
    for (int ni = 0; ni < 4; ++ni) {
      int row = m0 + wm * 64 + mi * 16 + kg * 4;
      int col = n0 + wn * 64 + ni * 16 + rl;
      #pragma unroll
      for (int r = 0; r < 4; ++r) {
        if constexpr (OUTF32)
          ((float*)C)[(size_t)(row + r) * N + col] = acc[mi][ni][r];
        else
          ((unsigned short*)C)[(size_t)(row + r) * N + col] = f2bf(acc[mi][ni][r]);
      }
    }
  }
}

// ---------------- RoPE (interleaved pairs) on Q and K; Q pre-scaled by SM_L2 --

__global__ void k_rope(unsigned short* __restrict__ qkv,
                       const float* __restrict__ tc, const float* __restrict__ ts) {
  int id = blockIdx.x * 256 + threadIdx.x;     // MROWS * 1280
  int row = id / 1280, p = id % 1280;
  int col, d;
  bool isq = (p < 1024);
  if (isq) { col = 2 * p;               d = p & 63; }
  else     { int pk = p - 1024; col = KOFF + 2 * pk; d = pk & 63; }
  int s = row & (SEQ - 1);
  float c = tc[s * 64 + d], sn = ts[s * 64 + d];
  unsigned int* pp = (unsigned int*)(qkv + (size_t)row * NQKV + col);
  unsigned int v = *pp;
  float x0 = bf2f((unsigned short)(v & 0xffffu));
  float x1 = bf2f((unsigned short)(v >> 16));
  float y0 = x0 * c - x1 * sn;
  float y1 = x1 * c + x0 * sn;
  if (isq) { y0 *= SM_L2; y1 *= SM_L2; }       // fold softmax scale * log2e into Q
  *pp = (unsigned int)f2bf(y0) | ((unsigned int)f2bf(y1) << 16);
}

// ---------------- flash attention, causal, GQA ------------------------------
// 8 waves x 16 q-rows (QB=128), KVBLK=64; GLL16 staging (R3); SWAPPED QK^T:
// St = mfma(K, Q) -> lane holds one q-row's scores -> lane-local softmax.

constexpr int QB = 128, KB = 64;
constexpr float THR = 8.0f;                    // defer-max threshold (log2 domain)

__global__ __launch_bounds__(512, 8) void k_attn(const unsigned short* __restrict__ qkv,
                                                 const unsigned short* __restrict__ vt,
                                                 unsigned short* __restrict__ obuf) {
  __shared__ unsigned short Ks[KB * DH];        // [64][128], chunk-XOR ^(row&7)
  __shared__ unsigned short Vs[DH * KB];        // [128][64], chunk-XOR ^(row&7)
  __shared__ unsigned short Pw[8][16 * 72];     // per-wave P, padded stride 72

  const int t = threadIdx.x, l = t & 63, w = t >> 6;
  const int rl = l & 15, kg = l >> 4;

  // complementary-pair decode: ids i and i+256 get q-tiles qt and 15-qt
  const int id = blockIdx.x;                    // [0, 512)
  const int b = id >> 8;
  const int u = id & 255;
  const int h = u >> 4;
  const int qtr = u & 15;
  const int qt = b ? (15 - qtr) : qtr;
  const int q0 = qt * QB;
  const int kvh = h >> 2;

  const unsigned short* qbase = qkv + (size_t)b * SEQ * NQKV;
  const unsigned short* kbase = qbase + KOFF + kvh * DH;
  const unsigned short* vtb = vt + (size_t)(b * NKVH + kvh) * DH * SEQ;

  // staging sources: K chunks c=i*512+t (row=c>>4, q=c&15); V chunks (row=c>>3, q=c&7)
  const unsigned short* kp[2];
  const unsigned short* vp[2];
  #pragma unroll
  for (int i = 0; i < 2; ++i) {
    int c = i * 512 + t;
    int krow = c >> 4, kq = c & 15;
    kp[i] = kbase + (size_t)krow * NQKV + ((kq ^ (krow & 7)) << 3);
    int vrow = c >> 3, vq = c & 7;
    vp[i] = vtb + (size_t)vrow * SEQ + ((vq ^ (vrow & 7)) << 3);
  }

  const int qw0 = q0 + w * 16;

  // Q fragments hoisted: lane holds Q[row=qw0+rl][k=kg*8+j], 4 k-steps
  short8 qF[4];
  {
    const size_t qr = (size_t)(qw0 + rl) * NQKV + h * DH;
    #pragma unroll
    for (int ks = 0; ks < 4; ++ks)
      qF[ks] = *(const short8*)(qbase + qr + ks * 32 + kg * 8);
  }

  f32x4 Oc[8] = {};
  float mr = -3e38f, lr = 0.f;                  // per-lane state for q = qw0 + rl

  unsigned short* pw = Pw[w];

  for (int kv0 = 0; kv0 < q0 + QB; kv0 += KB) {
    __syncthreads();
    #pragma unroll
    for (int i = 0; i < 2; ++i) {
      GLL16(kp[i] + (size_t)kv0 * NQKV, (char*)Ks + w * 1024 + i * 8192);
      GLL16(vp[i] + kv0,               (char*)Vs + w * 1024 + i * 8192);
    }
    __syncthreads();
    if (kv0 >= qw0 + 16) continue;   // fully masked for this wave (wave-uniform)

    // S^T = K Q : lane (rl,kg) holds S[q=qw0+rl][kv = kv0 + n*16 + kg*4 + r]
    f32x4 St[4] = {};
    __builtin_amdgcn_s_setprio(1);
    #pragma unroll
    for (int n = 0; n < 4; ++n) {
      const int krow = n * 16 + rl;
      #pragma unroll
      for (int ks = 0; ks < 4; ++ks) {
        short8 kF = *(const short8*)&Ks[krow * DH + (((ks * 4 + kg) ^ (rl & 7)) << 3)];
        St[n] = __builtin_amdgcn_mfma_f32_16x16x32_bf16(kF, qF[ks], St[n], 0, 0, 0);
      }
    }
    __builtin_amdgcn_s_setprio(0);

    // lane-local mask + max for q-row qw0+rl
    float mx = -3e38f;
    const bool diag = (kv0 + KB - 1) > qw0;      // tile straddles the diagonal
    if (diag) {
      const int thr = qw0 + rl - kv0;            // mask if kv-idx > thr
      #pragma unroll
      for (int n = 0; n < 4; ++n)
        #pragma unroll
        for (int r = 0; r < 4; ++r) {
          float s = St[n][r];
          if (n * 16 + kg * 4 + r > thr) s = -3e38f;
          St[n][r] = s;
          mx = fmaxf(mx, s);
        }
    } else {
      #pragma unroll
      for (int n = 0; n < 4; ++n)
        #pragma unroll
        for (int r = 0; r < 4; ++r) mx = fmaxf(mx, St[n][r]);
    }
    mx = fmaxf(mx, __shfl_xor(mx, 16));
    mx = fmaxf(mx, __shfl_xor(mx, 32));

    // deferred rescale (T13)
    const bool need = mx > mr + THR;
    if (__any(need)) {
      const float mnew = fmaxf(mr, mx);
      const float sf = exp2f(mr - mnew);
      mr = mnew;
      lr *= sf;
      float sfv[4];
      #pragma unroll
      for (int r = 0; r < 4; ++r) sfv[r] = __shfl(sf, kg * 4 + r, 16);
      #pragma unroll
      for (int c = 0; c < 8; ++c)
        #pragma unroll
        for (int r = 0; r < 4; ++r) Oc[c][r] *= sfv[r];
    }

    // exp2 + pack (cvt_pk) + lane-local sum; P[q=rl][kv] -> LDS as b64 writes
    float rs = 0.f;
    #pragma unroll
    for (int n = 0; n < 4; ++n) {
      float e0 = exp2f(St[n][0] - mr);
      float e1 = exp2f(St[n][1] - mr);
      float e2 = exp2f(St[n][2] - mr);
      float e3 = exp2f(St[n][3] - mr);
      rs += (e0 + e1) + (e2 + e3);
      uint2 d;
      d.x = cvtpk_bf16(e0, e1);
      d.y = cvtpk_bf16(e2, e3);
      *(uint2*)&pw[rl * 72 + n * 16 + kg * 4] = d;
    }
    rs += __shfl_xor(rs, 16);
    rs += __shfl_xor(rs, 32);
    lr += rs;

    // PV: A = P[16][64] (row=rl, k=kv), B = V (col=d, k=kv) from Vs rows
    short8 pF[2];
    #pragma unroll
    for (int ks2 = 0; ks2 < 2; ++ks2)
      pF[ks2] = *(const short8*)&pw[rl * 72 + ks2 * 32 + kg * 8];
    __builtin_amdgcn_s_setprio(1);
    #pragma unroll
    for (int c = 0; c < 8; ++c) {
      const int vrow = c * 16 + rl;
      #pragma unroll
      for (int ks2 = 0; ks2 < 2; ++ks2) {
        short8 vF = *(const short8*)&Vs[vrow * KB + (((ks2 * 4 + kg) ^ (rl & 7)) << 3)];
        Oc[c] = __builtin_amdgcn_mfma_f32_16x16x32_bf16(pF[ks2], vF, Oc[c], 0, 0, 0);
      }
    }
    __builtin_amdgcn_s_setprio(0);
  }

  // epilogue: O /= l (broadcast per output row), write bf16 [b*S+s][h*128+d]
  const float linv = 1.0f / lr;
  float inv[4];
  #pragma unroll
  for (int r = 0; r < 4; ++r) inv[r] = __shfl(linv, kg * 4 + r, 16);
  #pragma unroll
  for (int c = 0; c < 8; ++c)
    #pragma unroll
    for (int r = 0; r < 4; ++r) {
      int row = b * SEQ + qw0 + kg * 4 + r;
      obuf[(size_t)row * DMODEL + h * DH + c * 16 + rl] = f2bf(Oc[c][r] * inv[r]);
    }
}

// ---------------- launch ----------------------------------------------------

extern "C" void kernel_launch(void* const* d_in, const int* in_sizes, int n_in,
                              void* d_out, int out_size, void* d_ws, size_t ws_size,
                              hipStream_t stream) {
  const float* x  = (const float*)d_in[0];
  const float* wq = (const float*)d_in[1];
  const float* wk = (const float*)d_in[2];
  const float* wv = (const float*)d_in[3];
  const float* wo = (const float*)d_in[4];
  float* out = (float*)d_out;

  unsigned short* xb  = (unsigned short*)d_ws;                 // 4096x2048
  unsigned short* wT  = xb  + (size_t)MROWS * DMODEL;          // 3072x2048 (q|k|v transposed)
  unsigned short* woT = wT  + (size_t)NQKV * DMODEL;           // 2048x2048
  unsigned short* qkv = woT + (size_t)DMODEL * DMODEL;         // 4096x3072
  unsigned short* ob  = qkv + (size_t)MROWS * NQKV;            // 4096x2048
  float* tc = (float*)(ob + (size_t)MROWS * DMODEL);           // 2048x64
  float* ts = tc + SEQ * 64;
  // vt reuses the wT region (wT dead after the QKV GEMM)
  unsigned short* vtG = wT;

  k_tables<<<dim3(SEQ * 64 / 256), dim3(256), 0, stream>>>(tc, ts);
  k_castx<<<dim3(MROWS * DMODEL / 4 / 256), dim3(256), 0, stream>>>(x, xb);
  k_wtrans<<<dim3(DMODEL / 32, 64), dim3(32, 8), 0, stream>>>(wq, wT, DMODEL);
  k_wtrans<<<dim3(NKVH * DH / 32, 64), dim3(32, 8), 0, stream>>>(wk, wT + (size_t)DMODEL * 2048, NKVH * DH);
  k_wtrans<<<dim3(NKVH * DH / 32, 64), dim3(32, 8), 0, stream>>>(wv, wT + (size_t)VOFF * 2048, NKVH * DH);
  k_wtrans<<<dim3(DMODEL / 32, 64), dim3(32, 8), 0, stream>>>(wo, woT, DMODEL);

  k_gemm_bt<false><<<dim3(NQKV / BN, MROWS / BM), dim3(256), 0, stream>>>(
      xb, wT, qkv, MROWS, NQKV, DMODEL);
  k_rope<<<dim3(MROWS * 1280 / 256), dim3(256), 0, stream>>>(qkv, tc, ts);
  k_vtrans<<<dim3(SEQ / 32, DH / 32, BATCH * NKVH), dim3(32, 8), 0, stream>>>(qkv, vtG);
  k_attn<<<dim3(512), dim3(512), 0, stream>>>(qkv, vtG, ob);
  k_gemm_bt<true><<<dim3(DMODEL / BN, MROWS / BM), dim3(256), 0, stream>>>(
      ob, woT, out, MROWS, DMODEL, DMODEL);
}